// Round 3
// baseline (209.141 us; speedup 1.0000x reference)
//
#include <hip/hip_runtime.h>

typedef float fvec4 __attribute__((ext_vector_type(4)));

// Fast path: top_k==2, hidden==2048, n_tokens%4==0.
// 4 tokens per block, 256 threads, 2 float4/lane/token.
// All 8 slot/score loads hoisted (wave-uniform -> SGPR), all 16 row loads
// issuable before the first store -> deep MLP per wave instead of 1 iteration
// per short-lived block. NT stores keep the 64 MB write-once output from
// evicting gathered rows (Poisson duplicates re-hit L2/L3).
__global__ __launch_bounds__(256) void moe_gather_k2_h2048_t4(
    const float* __restrict__ moe,     // [total_slots, 2048]
    const float* __restrict__ scores,  // [total_slots]
    const int*   __restrict__ slots,   // [total_slots]
    float*       __restrict__ out) {   // [n_tokens, 2048]
    constexpr int NVEC = 512;          // 2048 / 4
    const int t0  = blockIdx.x * 4;
    const int tid = threadIdx.x;

    int   s[8];
    float w[8];
#pragma unroll
    for (int i = 0; i < 8; ++i) {
        s[i] = slots[2 * t0 + i];
        w[i] = scores[2 * t0 + i];
    }

    const fvec4* __restrict__ mo = (const fvec4*)moe;
    fvec4* __restrict__ ov = (fvec4*)out;

    fvec4 acc[8];
#pragma unroll
    for (int i = 0; i < 4; ++i) {
        const size_t r0 = (size_t)s[2 * i]     * NVEC;  // fvec4 units
        const size_t r1 = (size_t)s[2 * i + 1] * NVEC;
        fvec4 a0 = mo[r0 + tid];
        fvec4 a1 = mo[r0 + tid + 256];
        fvec4 b0 = mo[r1 + tid];
        fvec4 b1 = mo[r1 + tid + 256];
        acc[2 * i]     = w[2 * i] * a0 + w[2 * i + 1] * b0;
        acc[2 * i + 1] = w[2 * i] * a1 + w[2 * i + 1] * b1;
    }

#pragma unroll
    for (int i = 0; i < 4; ++i) {
        const size_t o = (size_t)(t0 + i) * NVEC;
        __builtin_nontemporal_store(acc[2 * i],     ov + o + tid);
        __builtin_nontemporal_store(acc[2 * i + 1], ov + o + tid + 256);
    }
}

// Generic fallback (any top_k <= 8, any hidden%4==0).
__global__ __launch_bounds__(256) void moe_gather_generic(
    const float* __restrict__ moe,
    const float* __restrict__ scores,
    const int*   __restrict__ slots,
    float*       __restrict__ out,
    int hidden, int top_k) {
    const int t   = blockIdx.x;
    const int tid = threadIdx.x;
    const int nvec = hidden >> 2;

    float w[8];
    const float4* rows[8];
    const int K = top_k > 8 ? 8 : top_k;
    for (int k = 0; k < K; ++k) {
        const int s = slots[(size_t)t * top_k + k];
        w[k] = scores[(size_t)t * top_k + k];
        rows[k] = (const float4*)(moe + (size_t)s * hidden);
    }

    float4* orow = (float4*)(out + (size_t)t * hidden);
    for (int v = tid; v < nvec; v += blockDim.x) {
        float4 acc = make_float4(0.f, 0.f, 0.f, 0.f);
        for (int k = 0; k < K; ++k) {
            float4 x = rows[k][v];
            acc.x += w[k] * x.x;
            acc.y += w[k] * x.y;
            acc.z += w[k] * x.z;
            acc.w += w[k] * x.w;
        }
        orow[v] = acc;
    }
}

extern "C" void kernel_launch(void* const* d_in, const int* in_sizes, int n_in,
                              void* d_out, int out_size, void* d_ws, size_t ws_size,
                              hipStream_t stream) {
    const float* moe    = (const float*)d_in[0];
    const float* scores = (const float*)d_in[1];
    const int*   slots  = (const int*)d_in[2];
    float* out = (float*)d_out;

    const int total_slots = in_sizes[1];                // 16384
    const int hidden      = in_sizes[0] / total_slots;  // 2048
    const int n_tokens    = out_size / hidden;          // 8192
    const int top_k       = total_slots / n_tokens;     // 2

    if (top_k == 2 && hidden == 2048 && (n_tokens % 4) == 0) {
        moe_gather_k2_h2048_t4<<<n_tokens / 4, 256, 0, stream>>>(moe, scores,
                                                                 slots, out);
    } else {
        moe_gather_generic<<<n_tokens, 256, 0, stream>>>(moe, scores, slots, out,
                                                         hidden, top_k);
    }
}